// Round 6
// baseline (224.699 us; speedup 1.0000x reference)
//
#include <hip/hip_runtime.h>
#include <hip/hip_bf16.h>
#include <math.h>

typedef __bf16 bf16_t;
typedef __bf16 bf16x8 __attribute__((ext_vector_type(8)));
typedef __bf16 bf16x4 __attribute__((ext_vector_type(4)));
typedef float  f32x4  __attribute__((ext_vector_type(4)));

#define D_MODEL 1024
#define NH      16
#define HD      64
#define BATCH   2
#define SEQ     2048
#define MROWS   (BATCH*SEQ)   // 4096
#define QKVN    (3*D_MODEL)   // 3072
#define FA_PAD  72            // LDS row stride: frag b128 reads at wave64 structural min
#define SCALE_LOG2E 0.18033688011112042f   // 0.125 * log2(e)

__device__ __forceinline__ void async_cp16(const bf16_t* g, bf16_t* l) {
    __builtin_amdgcn_global_load_lds(
        (const __attribute__((address_space(1))) void*)g,
        (__attribute__((address_space(3))) void*)l,
        16, 0, 0);
}

// ---------------- fp32 -> bf16 convert, all three inputs in one launch ------
__global__ void cvt_all(const float* __restrict__ x, const float* __restrict__ wq,
                        const float* __restrict__ wo,
                        bf16_t* __restrict__ xb, bf16_t* __restrict__ wqb,
                        bf16_t* __restrict__ wob) {
    const int nx = MROWS * D_MODEL, nq = QKVN * D_MODEL;
    int i = (blockIdx.x * blockDim.x + threadIdx.x) * 4;
    const float* s; bf16_t* d; int off;
    if (i < nx)           { s = x;  d = xb;  off = i; }
    else if (i < nx + nq) { s = wq; d = wqb; off = i - nx; }
    else                  { s = wo; d = wob; off = i - nx - nq; }
    float4 v = *(const float4*)(s + off);
    d[off]     = (bf16_t)v.x;
    d[off + 1] = (bf16_t)v.y;
    d[off + 2] = (bf16_t)v.z;
    d[off + 3] = (bf16_t)v.w;
}

// ---------------- NT GEMM, BK=64: C[M,N] = A[M,K] * B[N,K]^T ----------------
// Block tile 128 x (NI*32), K-step 64 split as two 32-col LDS sub-tiles
// (keeps the lane-x16B DMA layout and the minimal bank pattern). Halves the
// barrier count vs BK=32; 2x MFMA per LDS fragment read.
template <typename OutT, int NI>
__global__ __launch_bounds__(256) void gemm_nt(const bf16_t* __restrict__ A,
                                               const bf16_t* __restrict__ Bm,
                                               OutT* __restrict__ C,
                                               int M, int N, int K) {
    __shared__ __align__(16) bf16_t As[2][128 * 32];
    __shared__ __align__(16) bf16_t Bs[2][NI * 32 * 32];
    const int tid  = threadIdx.x;
    const int w    = tid >> 6;
    const int lane = tid & 63;
    const int quad = lane >> 4;
    const int l16  = lane & 15;
    const int m0   = blockIdx.x * 128;
    const int n0   = blockIdx.y * (NI * 32);
    const int wm   = (w >> 1) * 64;
    const int wn   = (w & 1) * (NI * 16);

    f32x4 acc[4][NI];
    #pragma unroll
    for (int i = 0; i < 4; i++)
        #pragma unroll
        for (int j = 0; j < NI; j++)
            acc[i][j] = (f32x4){0.f, 0.f, 0.f, 0.f};

    const bf16_t* Ag0 = A  + (size_t)(m0 + (tid >> 2)) * K + (tid & 3) * 8;
    const bf16_t* Ag1 = Ag0 + (size_t)64 * K;
    const bf16_t* Bg0 = Bm + (size_t)(n0 + (tid >> 2)) * K + (tid & 3) * 8;
    const bf16_t* Bg1 = Bg0 + (size_t)64 * K;

    for (int k0 = 0; k0 < K; k0 += 64) {
        #pragma unroll
        for (int kk = 0; kk < 2; kk++) {
            const int kc = k0 + kk * 32;
            async_cp16(Ag0 + kc, &As[kk][(size_t)tid * 8]);
            async_cp16(Ag1 + kc, &As[kk][((size_t)tid + 256) * 8]);
            async_cp16(Bg0 + kc, &Bs[kk][(size_t)tid * 8]);
            if (NI == 4) async_cp16(Bg1 + kc, &Bs[kk][((size_t)tid + 256) * 8]);
        }
        __syncthreads();   // DMA drained + all waves arrived

        #pragma unroll
        for (int kk = 0; kk < 2; kk++) {
            bf16x8 af[4], bfr[NI];
            #pragma unroll
            for (int mi = 0; mi < 4; mi++)
                af[mi] = *(const bf16x8*)&As[kk][(wm + mi * 16 + l16) * 32 + quad * 8];
            #pragma unroll
            for (int ni = 0; ni < NI; ni++)
                bfr[ni] = *(const bf16x8*)&Bs[kk][(wn + ni * 16 + l16) * 32 + quad * 8];
            #pragma unroll
            for (int mi = 0; mi < 4; mi++)
                #pragma unroll
                for (int ni = 0; ni < NI; ni++)
                    acc[mi][ni] = __builtin_amdgcn_mfma_f32_16x16x32_bf16(
                        af[mi], bfr[ni], acc[mi][ni], 0, 0, 0);
        }
        __syncthreads();   // readers done before next DMA overwrites
    }

    #pragma unroll
    for (int mi = 0; mi < 4; mi++)
        #pragma unroll
        for (int ni = 0; ni < NI; ni++) {
            const int col = n0 + wn + ni * 16 + l16;
            #pragma unroll
            for (int r = 0; r < 4; r++) {
                const int row = m0 + wm + mi * 16 + quad * 4 + r;
                C[(size_t)row * N + col] = (OutT)acc[mi][ni][r];
            }
        }
}

// ---------------- RoPE + head split + V transpose (coalesced) ----------------
__global__ __launch_bounds__(256) void rope_split(const bf16_t* __restrict__ qkv,
                                                  const int* __restrict__ pos,
                                                  bf16_t* __restrict__ Qh,
                                                  bf16_t* __restrict__ Kh,
                                                  bf16_t* __restrict__ VT) {
    __shared__ bf16_t vs[128][FA_PAD];
    const int tid   = threadIdx.x;
    const int s_loc = tid >> 1;
    const int half  = tid & 1;
    const int s0    = blockIdx.x * 128;
    const int bh    = blockIdx.y;
    const int b     = bh >> 4, h = bh & 15;
    const int s     = s0 + s_loc;

    const bf16_t* row = qkv + (size_t)(b * SEQ + s) * QKVN + h * HD + half * 32;

    bf16_t qbuf[32], kbuf[32], vbuf[32];
    #pragma unroll
    for (int j = 0; j < 4; j++) {
        *(bf16x8*)&qbuf[j * 8] = *(const bf16x8*)(row + j * 8);
        *(bf16x8*)&kbuf[j * 8] = *(const bf16x8*)(row + D_MODEL + j * 8);
        *(bf16x8*)&vbuf[j * 8] = *(const bf16x8*)(row + 2 * D_MODEL + j * 8);
    }

    const float pf = (float)pos[s];
    #pragma unroll
    for (int p = 0; p < 16; p++) {
        const int d2 = half * 16 + p;
        const float inv = __expf(-0.28782313662425575f * (float)d2);
        const float f = pf * inv;
        const float c = cosf(f), sn = sinf(f);
        float qe = (float)qbuf[2 * p], qo = (float)qbuf[2 * p + 1];
        float ke = (float)kbuf[2 * p], ko = (float)kbuf[2 * p + 1];
        qbuf[2 * p]     = (bf16_t)(qe * c - qo * sn);
        qbuf[2 * p + 1] = (bf16_t)(qo * c + qe * sn);
        kbuf[2 * p]     = (bf16_t)(ke * c - ko * sn);
        kbuf[2 * p + 1] = (bf16_t)(ko * c + ke * sn);
    }

    bf16_t* qdst = Qh + ((size_t)bh * SEQ + s) * HD + half * 32;
    bf16_t* kdst = Kh + ((size_t)bh * SEQ + s) * HD + half * 32;
    #pragma unroll
    for (int j = 0; j < 4; j++) {
        *(bf16x8*)(qdst + j * 8) = *(bf16x8*)&qbuf[j * 8];
        *(bf16x8*)(kdst + j * 8) = *(bf16x8*)&kbuf[j * 8];
        *(bf16x8*)&vs[s_loc][half * 32 + j * 8] = *(bf16x8*)&vbuf[j * 8];
    }
    __syncthreads();

    const int d  = tid >> 2;
    const int sc = tid & 3;
    bf16_t tmp[32];
    #pragma unroll
    for (int i = 0; i < 32; i++) tmp[i] = vs[sc * 32 + i][d];
    bf16_t* vdst = VT + ((size_t)bh * HD + d) * SEQ + s0 + sc * 32;
    #pragma unroll
    for (int j = 0; j < 4; j++)
        *(bf16x8*)(vdst + j * 8) = *(bf16x8*)&tmp[j * 8];
}

// ---------------- causal flash attention: folded pairs, 8 waves -------------
// Round-4 structure (512 thr, pair-fold, dbuf V, one barrier/iter) but K
// fragments are read DIRECTLY from global (contiguous b128, 64B segments,
// L2-resident via XCD swizzle) — removes K staging + K ds_reads from the
// LDS pipe. Max-free softmax via S^T = K*Q^T.
__global__ __launch_bounds__(512) void flash_attn(const bf16_t* __restrict__ Qh,
                                                  const bf16_t* __restrict__ Kh,
                                                  const bf16_t* __restrict__ VT,
                                                  bf16_t* __restrict__ AO) {
    __shared__ __align__(16) bf16_t Vs[2][64 * FA_PAD];    // [buf][d][kv] 18.4 KB
    __shared__ __align__(16) bf16_t pT[8][16][FA_PAD];     // per-wave [q][kv] 18.4 KB

    const int tid  = threadIdx.x;
    const int w    = tid >> 6;
    const int lane = tid & 63;
    const int quad = lane >> 4;
    const int l16  = lane & 15;
    const int wq   = w & 3;        // wave's 16-row slice within its q-tile
    const int g    = w >> 2;       // 0 = big tile, 1 = small tile

    const int bid  = blockIdx.x;
    const int xcd  = bid & 7;
    const int mm   = bid >> 3;                 // 0..63
    const int bh   = (mm >> 4) * 8 + xcd;      // same-bh blocks share an XCD
    const int pair = mm & 15;                  // pair 0 (longest) dispatches first
    const int qt_big = 31 - pair;
    const int my_qt  = g ? pair : qt_big;
    const int niter  = qt_big + 1;             // 17..32

    const bf16_t* Qb = Qh + (size_t)bh * SEQ * HD;
    const bf16_t* Kb = Kh + (size_t)bh * SEQ * HD;
    const bf16_t* Vb = VT + (size_t)bh * HD * SEQ;

    const int q0 = my_qt * 64 + wq * 16;
    const bf16x8 aq0 = *(const bf16x8*)(Qb + (size_t)(q0 + l16) * HD + quad * 8);
    const bf16x8 aq1 = *(const bf16x8*)(Qb + (size_t)(q0 + l16) * HD + 32 + quad * 8);

    // V staging: 512 threads, one b128 each: row = tid>>3 (d), col = (tid&7)*8 (kv)
    const int srow = tid >> 3, scol = (tid & 7) * 8;
    const int lds_off = srow * FA_PAD + scol;

    f32x4 o[4];
    #pragma unroll
    for (int i = 0; i < 4; i++) o[i] = (f32x4){0.f, 0.f, 0.f, 0.f};
    float lsum = 0.f;

    // prologue: V tile 0 -> buf 0
    bf16x8 pV = *(const bf16x8*)(Vb + (size_t)srow * SEQ + scol);
    *(bf16x8*)&Vs[0][lds_off] = pV;

    for (int kt = 0; kt < niter; ++kt) {
        const int cur = kt & 1;
        // prefetch next V tile before the barrier (spans barrier-wait + compute)
        if (kt + 1 < niter) {
            const int kn = (kt + 1) * 64;
            pV = *(const bf16x8*)(Vb + (size_t)srow * SEQ + kn + scol);
        }
        __syncthreads();   // Vs[cur] visible; everyone done reading Vs[cur^1]

        if (kt <= my_qt) {
            const int k0 = kt * 64;
            const bool diag = (kt == my_qt);
            const bf16_t* VsC = &Vs[cur][0];

            #pragma unroll
            for (int ni = 0; ni < 4; ni++) {
                if (diag && ni > wq) {   // fully-masked kv sub-tile
                    *(bf16x4*)&pT[w][l16][ni * 16 + quad * 4] = (bf16x4){0, 0, 0, 0};
                    continue;
                }
                // K fragment direct from global: 16 rows x 64B segments, L2-hit
                const bf16_t* kp = Kb + (size_t)(k0 + ni * 16 + l16) * HD + quad * 8;
                bf16x8 kb0 = *(const bf16x8*)kp;
                bf16x8 kb1 = *(const bf16x8*)(kp + 32);
                f32x4 t = (f32x4){0.f, 0.f, 0.f, 0.f};
                t = __builtin_amdgcn_mfma_f32_16x16x32_bf16(kb0, aq0, t, 0, 0, 0);  // S^T
                t = __builtin_amdgcn_mfma_f32_16x16x32_bf16(kb1, aq1, t, 0, 0, 0);
                bf16x4 pk;
                #pragma unroll
                for (int r = 0; r < 4; r++) {
                    float pv = exp2f(t[r] * SCALE_LOG2E);
                    if (diag && (ni * 16 + quad * 4 + r > wq * 16 + l16)) pv = 0.f;
                    lsum += pv;
                    pk[r] = (bf16_t)pv;
                }
                *(bf16x4*)&pT[w][l16][ni * 16 + quad * 4] = pk;
            }

            // PV: pT is wave-private -> no barrier
            #pragma unroll
            for (int ks = 0; ks < 2; ks++) {
                if (diag && wq * 16 + 15 < ks * 32) continue;
                bf16x8 ap = *(const bf16x8*)&pT[w][l16][ks * 32 + quad * 8];
                #pragma unroll
                for (int ni = 0; ni < 4; ni++) {
                    bf16x8 vb = *(const bf16x8*)&VsC[(ni * 16 + l16) * FA_PAD + ks * 32 + quad * 8];
                    o[ni] = __builtin_amdgcn_mfma_f32_16x16x32_bf16(ap, vb, o[ni], 0, 0, 0);
                }
            }
        }

        if (kt + 1 < niter)
            *(bf16x8*)&Vs[cur ^ 1][lds_off] = pV;
    }

    // finalize: reduce lsum over quads, redistribute to C-layout rows
    lsum += __shfl_xor(lsum, 16);
    lsum += __shfl_xor(lsum, 32);
    f32x4 linv;
    #pragma unroll
    for (int r = 0; r < 4; r++)
        linv[r] = 1.0f / __shfl(lsum, quad * 4 + r);

    const int b = bh >> 4, h = bh & 15;
    #pragma unroll
    for (int ni = 0; ni < 4; ni++) {
        #pragma unroll
        for (int r = 0; r < 4; r++) {
            const size_t row = (size_t)b * SEQ + q0 + quad * 4 + r;
            AO[row * D_MODEL + h * HD + ni * 16 + l16] = (bf16_t)(o[ni][r] * linv[r]);
        }
    }
}

// ---------------- launcher ----------------
extern "C" void kernel_launch(void* const* d_in, const int* in_sizes, int n_in,
                              void* d_out, int out_size, void* d_ws, size_t ws_size,
                              hipStream_t stream) {
    const float* x     = (const float*)d_in[0];
    const float* w_qkv = (const float*)d_in[1];
    const float* w_o   = (const float*)d_in[2];
    const int*   tpos  = (const int*)d_in[3];
    float*       out   = (float*)d_out;

    char* ws = (char*)d_ws;
    bf16_t* xb  = (bf16_t*)(ws);                 //  8 MB
    bf16_t* wqb = (bf16_t*)(ws + 8388608);       //  6 MB
    bf16_t* wob = (bf16_t*)(ws + 14680064);      //  2 MB
    bf16_t* qkv = (bf16_t*)(ws + 16777216);      // 24 MB
    bf16_t* Qh  = (bf16_t*)(ws + 41943040);      //  8 MB
    bf16_t* Kh  = (bf16_t*)(ws + 50331648);      //  8 MB
    bf16_t* VT  = (bf16_t*)(ws + 58720256);      //  8 MB
    bf16_t* AO  = (bf16_t*)(ws + 67108864);      //  8 MB

    cvt_all<<<8192, 256, 0, stream>>>(x, w_qkv, w_o, xb, wqb, wob);

    // qkv = x @ w_qkv^T : M=4096, N=3072, K=1024
    gemm_nt<bf16_t, 4><<<dim3(32, 24), 256, 0, stream>>>(xb, wqb, qkv, MROWS, QKVN, D_MODEL);

    rope_split<<<dim3(SEQ / 128, BATCH * NH), 256, 0, stream>>>(qkv, tpos, Qh, Kh, VT);

    flash_attn<<<512, 512, 0, stream>>>(Qh, Kh, VT, AO);

    // out = AO @ w_o^T : M=4096, N=1024, K=1024 (fp32 out)
    gemm_nt<float, 2><<<dim3(32, 16), 256, 0, stream>>>(AO, wob, out, MROWS, D_MODEL, D_MODEL);
}

// Round 7
// 217.405 us; speedup vs baseline: 1.0336x; 1.0336x over previous
//
#include <hip/hip_runtime.h>
#include <hip/hip_bf16.h>
#include <math.h>

typedef __bf16 bf16_t;
typedef __bf16 bf16x8 __attribute__((ext_vector_type(8)));
typedef __bf16 bf16x4 __attribute__((ext_vector_type(4)));
typedef float  f32x4  __attribute__((ext_vector_type(4)));

#define D_MODEL 1024
#define NH      16
#define HD      64
#define BATCH   2
#define SEQ     2048
#define MROWS   (BATCH*SEQ)   // 4096
#define QKVN    (3*D_MODEL)   // 3072
#define FA_PAD  72            // LDS row stride: frag b128 reads at wave64 structural min
#define SCALE_LOG2E 0.18033688011112042f   // 0.125 * log2(e)

__device__ __forceinline__ void async_cp16(const bf16_t* g, bf16_t* l) {
    __builtin_amdgcn_global_load_lds(
        (const __attribute__((address_space(1))) void*)g,
        (__attribute__((address_space(3))) void*)l,
        16, 0, 0);
}

// ---------------- fp32 -> bf16 convert, all three inputs in one launch ------
__global__ void cvt_all(const float* __restrict__ x, const float* __restrict__ wq,
                        const float* __restrict__ wo,
                        bf16_t* __restrict__ xb, bf16_t* __restrict__ wqb,
                        bf16_t* __restrict__ wob) {
    const int nx = MROWS * D_MODEL, nq = QKVN * D_MODEL;
    int i = (blockIdx.x * blockDim.x + threadIdx.x) * 4;
    const float* s; bf16_t* d; int off;
    if (i < nx)           { s = x;  d = xb;  off = i; }
    else if (i < nx + nq) { s = wq; d = wqb; off = i - nx; }
    else                  { s = wo; d = wob; off = i - nx - nq; }
    float4 v = *(const float4*)(s + off);
    d[off]     = (bf16_t)v.x;
    d[off + 1] = (bf16_t)v.y;
    d[off + 2] = (bf16_t)v.z;
    d[off + 3] = (bf16_t)v.w;
}

// ---------------- NT GEMM, BK=64: C[M,N] = A[M,K] * B[N,K]^T ----------------
template <typename OutT, int NI>
__global__ __launch_bounds__(256) void gemm_nt(const bf16_t* __restrict__ A,
                                               const bf16_t* __restrict__ Bm,
                                               OutT* __restrict__ C,
                                               int M, int N, int K) {
    __shared__ __align__(16) bf16_t As[2][128 * 32];
    __shared__ __align__(16) bf16_t Bs[2][NI * 32 * 32];
    const int tid  = threadIdx.x;
    const int w    = tid >> 6;
    const int lane = tid & 63;
    const int quad = lane >> 4;
    const int l16  = lane & 15;
    const int m0   = blockIdx.x * 128;
    const int n0   = blockIdx.y * (NI * 32);
    const int wm   = (w >> 1) * 64;
    const int wn   = (w & 1) * (NI * 16);

    f32x4 acc[4][NI];
    #pragma unroll
    for (int i = 0; i < 4; i++)
        #pragma unroll
        for (int j = 0; j < NI; j++)
            acc[i][j] = (f32x4){0.f, 0.f, 0.f, 0.f};

    const bf16_t* Ag0 = A  + (size_t)(m0 + (tid >> 2)) * K + (tid & 3) * 8;
    const bf16_t* Ag1 = Ag0 + (size_t)64 * K;
    const bf16_t* Bg0 = Bm + (size_t)(n0 + (tid >> 2)) * K + (tid & 3) * 8;
    const bf16_t* Bg1 = Bg0 + (size_t)64 * K;

    for (int k0 = 0; k0 < K; k0 += 64) {
        #pragma unroll
        for (int kk = 0; kk < 2; kk++) {
            const int kc = k0 + kk * 32;
            async_cp16(Ag0 + kc, &As[kk][(size_t)tid * 8]);
            async_cp16(Ag1 + kc, &As[kk][((size_t)tid + 256) * 8]);
            async_cp16(Bg0 + kc, &Bs[kk][(size_t)tid * 8]);
            if (NI == 4) async_cp16(Bg1 + kc, &Bs[kk][((size_t)tid + 256) * 8]);
        }
        __syncthreads();   // DMA drained + all waves arrived

        #pragma unroll
        for (int kk = 0; kk < 2; kk++) {
            bf16x8 af[4], bfr[NI];
            #pragma unroll
            for (int mi = 0; mi < 4; mi++)
                af[mi] = *(const bf16x8*)&As[kk][(wm + mi * 16 + l16) * 32 + quad * 8];
            #pragma unroll
            for (int ni = 0; ni < NI; ni++)
                bfr[ni] = *(const bf16x8*)&Bs[kk][(wn + ni * 16 + l16) * 32 + quad * 8];
            #pragma unroll
            for (int mi = 0; mi < 4; mi++)
                #pragma unroll
                for (int ni = 0; ni < NI; ni++)
                    acc[mi][ni] = __builtin_amdgcn_mfma_f32_16x16x32_bf16(
                        af[mi], bfr[ni], acc[mi][ni], 0, 0, 0);
        }
        __syncthreads();   // readers done before next DMA overwrites
    }

    #pragma unroll
    for (int mi = 0; mi < 4; mi++)
        #pragma unroll
        for (int ni = 0; ni < NI; ni++) {
            const int col = n0 + wn + ni * 16 + l16;
            #pragma unroll
            for (int r = 0; r < 4; r++) {
                const int row = m0 + wm + mi * 16 + quad * 4 + r;
                C[(size_t)row * N + col] = (OutT)acc[mi][ni][r];
            }
        }
}

// ---------------- RoPE + head split + V transpose (coalesced) ----------------
__global__ __launch_bounds__(256) void rope_split(const bf16_t* __restrict__ qkv,
                                                  const int* __restrict__ pos,
                                                  bf16_t* __restrict__ Qh,
                                                  bf16_t* __restrict__ Kh,
                                                  bf16_t* __restrict__ VT) {
    __shared__ bf16_t vs[128][FA_PAD];
    const int tid   = threadIdx.x;
    const int s_loc = tid >> 1;
    const int half  = tid & 1;
    const int s0    = blockIdx.x * 128;
    const int bh    = blockIdx.y;
    const int b     = bh >> 4, h = bh & 15;
    const int s     = s0 + s_loc;

    const bf16_t* row = qkv + (size_t)(b * SEQ + s) * QKVN + h * HD + half * 32;

    bf16_t qbuf[32], kbuf[32], vbuf[32];
    #pragma unroll
    for (int j = 0; j < 4; j++) {
        *(bf16x8*)&qbuf[j * 8] = *(const bf16x8*)(row + j * 8);
        *(bf16x8*)&kbuf[j * 8] = *(const bf16x8*)(row + D_MODEL + j * 8);
        *(bf16x8*)&vbuf[j * 8] = *(const bf16x8*)(row + 2 * D_MODEL + j * 8);
    }

    const float pf = (float)pos[s];
    #pragma unroll
    for (int p = 0; p < 16; p++) {
        const int d2 = half * 16 + p;
        const float inv = __expf(-0.28782313662425575f * (float)d2);
        const float f = pf * inv;
        const float c = cosf(f), sn = sinf(f);
        float qe = (float)qbuf[2 * p], qo = (float)qbuf[2 * p + 1];
        float ke = (float)kbuf[2 * p], ko = (float)kbuf[2 * p + 1];
        qbuf[2 * p]     = (bf16_t)(qe * c - qo * sn);
        qbuf[2 * p + 1] = (bf16_t)(qo * c + qe * sn);
        kbuf[2 * p]     = (bf16_t)(ke * c - ko * sn);
        kbuf[2 * p + 1] = (bf16_t)(ko * c + ke * sn);
    }

    bf16_t* qdst = Qh + ((size_t)bh * SEQ + s) * HD + half * 32;
    bf16_t* kdst = Kh + ((size_t)bh * SEQ + s) * HD + half * 32;
    #pragma unroll
    for (int j = 0; j < 4; j++) {
        *(bf16x8*)(qdst + j * 8) = *(bf16x8*)&qbuf[j * 8];
        *(bf16x8*)(kdst + j * 8) = *(bf16x8*)&kbuf[j * 8];
        *(bf16x8*)&vs[s_loc][half * 32 + j * 8] = *(bf16x8*)&vbuf[j * 8];
    }
    __syncthreads();

    const int d  = tid >> 2;
    const int sc = tid & 3;
    bf16_t tmp[32];
    #pragma unroll
    for (int i = 0; i < 32; i++) tmp[i] = vs[sc * 32 + i][d];
    bf16_t* vdst = VT + ((size_t)bh * HD + d) * SEQ + s0 + sc * 32;
    #pragma unroll
    for (int j = 0; j < 4; j++)
        *(bf16x8*)(vdst + j * 8) = *(bf16x8*)&tmp[j * 8];
}

// ---------------- causal flash attention: folded pairs, 8 waves -------------
// Round-4 structure (512 thr, pair-fold, dbuf V in LDS, one barrier/iter) with
// K fragments held in REGISTERS, prefetched one kv-tile ahead (per-ni: MFMA
// consumes kf[ni], then kf[ni] reloads for tile kt+1 — load issues a full
// iteration before use, L2 latency hidden). K leaves the LDS pipe entirely;
// V+P stay on LDS. Two pipes ~balanced. Max-free softmax via S^T = K*Q^T.
__global__ __launch_bounds__(512) void flash_attn(const bf16_t* __restrict__ Qh,
                                                  const bf16_t* __restrict__ Kh,
                                                  const bf16_t* __restrict__ VT,
                                                  bf16_t* __restrict__ AO) {
    __shared__ __align__(16) bf16_t Vs[2][64 * FA_PAD];    // [buf][d][kv] 18.4 KB
    __shared__ __align__(16) bf16_t pT[8][16][FA_PAD];     // per-wave [q][kv] 18.4 KB

    const int tid  = threadIdx.x;
    const int w    = tid >> 6;
    const int lane = tid & 63;
    const int quad = lane >> 4;
    const int l16  = lane & 15;
    const int wq   = w & 3;        // wave's 16-row slice within its q-tile
    const int g    = w >> 2;       // 0 = big tile, 1 = small tile

    const int bid  = blockIdx.x;
    const int xcd  = bid & 7;
    const int mm   = bid >> 3;                 // 0..63
    const int bh   = (mm >> 4) * 8 + xcd;      // same-bh blocks share an XCD
    const int pair = mm & 15;                  // pair 0 (longest) dispatches first
    const int qt_big = 31 - pair;
    const int my_qt  = g ? pair : qt_big;
    const int niter  = qt_big + 1;             // 17..32

    const bf16_t* Qb = Qh + (size_t)bh * SEQ * HD;
    const bf16_t* Kb = Kh + (size_t)bh * SEQ * HD;
    const bf16_t* Vb = VT + (size_t)bh * HD * SEQ;

    const int q0 = my_qt * 64 + wq * 16;
    const bf16x8 aq0 = *(const bf16x8*)(Qb + (size_t)(q0 + l16) * HD + quad * 8);
    const bf16x8 aq1 = *(const bf16x8*)(Qb + (size_t)(q0 + l16) * HD + 32 + quad * 8);

    // V staging: 512 threads, one b128 each: row = tid>>3 (d), col = (tid&7)*8 (kv)
    const int srow = tid >> 3, scol = (tid & 7) * 8;
    const int lds_off = srow * FA_PAD + scol;

    f32x4 o[4];
    #pragma unroll
    for (int i = 0; i < 4; i++) o[i] = (f32x4){0.f, 0.f, 0.f, 0.f};
    float lsum = 0.f;

    // prologue: V tile 0 -> buf 0; K frags for tile 0 -> registers
    bf16x8 pV = *(const bf16x8*)(Vb + (size_t)srow * SEQ + scol);
    *(bf16x8*)&Vs[0][lds_off] = pV;
    const bf16_t* kfp = Kb + (size_t)l16 * HD + quad * 8;   // lane's K-frag base
    bf16x8 kf[8];
    #pragma unroll
    for (int ni = 0; ni < 4; ni++) {
        kf[2 * ni]     = *(const bf16x8*)(kfp + (size_t)ni * 16 * HD);
        kf[2 * ni + 1] = *(const bf16x8*)(kfp + (size_t)ni * 16 * HD + 32);
    }

    for (int kt = 0; kt < niter; ++kt) {
        const int cur = kt & 1;
        // prefetch next V tile before the barrier (spans barrier-wait + compute)
        if (kt + 1 < niter) {
            const int kn = (kt + 1) * 64;
            pV = *(const bf16x8*)(Vb + (size_t)srow * SEQ + kn + scol);
        }
        __syncthreads();   // Vs[cur] visible; everyone done reading Vs[cur^1]

        if (kt <= my_qt) {
            const bool diag = (kt == my_qt);
            const bool pfK  = (kt + 1 <= my_qt);           // wave-uniform
            const bf16_t* kfn = kfp + (size_t)(kt + 1) * 64 * HD;
            const bf16_t* VsC = &Vs[cur][0];

            #pragma unroll
            for (int ni = 0; ni < 4; ni++) {
                const bool skip = diag && ni > wq;         // fully-masked kv sub-tile
                f32x4 t = (f32x4){0.f, 0.f, 0.f, 0.f};
                if (!skip) {
                    t = __builtin_amdgcn_mfma_f32_16x16x32_bf16(kf[2 * ni],     aq0, t, 0, 0, 0);
                    t = __builtin_amdgcn_mfma_f32_16x16x32_bf16(kf[2 * ni + 1], aq1, t, 0, 0, 0);
                }
                // reload kf[ni] for tile kt+1 right after last use: ~1 iter of latency slack
                if (pfK) {
                    kf[2 * ni]     = *(const bf16x8*)(kfn + (size_t)ni * 16 * HD);
                    kf[2 * ni + 1] = *(const bf16x8*)(kfn + (size_t)ni * 16 * HD + 32);
                }
                if (!skip) {
                    bf16x4 pk;
                    #pragma unroll
                    for (int r = 0; r < 4; r++) {
                        float pv = exp2f(t[r] * SCALE_LOG2E);
                        if (diag && (ni * 16 + quad * 4 + r > wq * 16 + l16)) pv = 0.f;
                        lsum += pv;
                        pk[r] = (bf16_t)pv;
                    }
                    *(bf16x4*)&pT[w][l16][ni * 16 + quad * 4] = pk;
                } else {
                    *(bf16x4*)&pT[w][l16][ni * 16 + quad * 4] = (bf16x4){0, 0, 0, 0};
                }
            }

            // PV: pT is wave-private -> no barrier
            #pragma unroll
            for (int ks = 0; ks < 2; ks++) {
                if (diag && wq * 16 + 15 < ks * 32) continue;
                bf16x8 ap = *(const bf16x8*)&pT[w][l16][ks * 32 + quad * 8];
                #pragma unroll
                for (int ni = 0; ni < 4; ni++) {
                    bf16x8 vb = *(const bf16x8*)&VsC[(ni * 16 + l16) * FA_PAD + ks * 32 + quad * 8];
                    o[ni] = __builtin_amdgcn_mfma_f32_16x16x32_bf16(ap, vb, o[ni], 0, 0, 0);
                }
            }
        }

        if (kt + 1 < niter)
            *(bf16x8*)&Vs[cur ^ 1][lds_off] = pV;
    }

    // finalize: reduce lsum over quads, redistribute to C-layout rows
    lsum += __shfl_xor(lsum, 16);
    lsum += __shfl_xor(lsum, 32);
    f32x4 linv;
    #pragma unroll
    for (int r = 0; r < 4; r++)
        linv[r] = 1.0f / __shfl(lsum, quad * 4 + r);

    const int b = bh >> 4, h = bh & 15;
    #pragma unroll
    for (int ni = 0; ni < 4; ni++) {
        #pragma unroll
        for (int r = 0; r < 4; r++) {
            const size_t row = (size_t)b * SEQ + q0 + quad * 4 + r;
            AO[row * D_MODEL + h * HD + ni * 16 + l16] = (bf16_t)(o[ni][r] * linv[r]);
        }
    }
}

// ---------------- launcher ----------------
extern "C" void kernel_launch(void* const* d_in, const int* in_sizes, int n_in,
                              void* d_out, int out_size, void* d_ws, size_t ws_size,
                              hipStream_t stream) {
    const float* x     = (const float*)d_in[0];
    const float* w_qkv = (const float*)d_in[1];
    const float* w_o   = (const float*)d_in[2];
    const int*   tpos  = (const int*)d_in[3];
    float*       out   = (float*)d_out;

    char* ws = (char*)d_ws;
    bf16_t* xb  = (bf16_t*)(ws);                 //  8 MB
    bf16_t* wqb = (bf16_t*)(ws + 8388608);       //  6 MB
    bf16_t* wob = (bf16_t*)(ws + 14680064);      //  2 MB
    bf16_t* qkv = (bf16_t*)(ws + 16777216);      // 24 MB
    bf16_t* Qh  = (bf16_t*)(ws + 41943040);      //  8 MB
    bf16_t* Kh  = (bf16_t*)(ws + 50331648);      //  8 MB
    bf16_t* VT  = (bf16_t*)(ws + 58720256);      //  8 MB
    bf16_t* AO  = (bf16_t*)(ws + 67108864);      //  8 MB

    cvt_all<<<8192, 256, 0, stream>>>(x, w_qkv, w_o, xb, wqb, wob);

    // qkv = x @ w_qkv^T : M=4096, N=3072, K=1024
    gemm_nt<bf16_t, 4><<<dim3(32, 24), 256, 0, stream>>>(xb, wqb, qkv, MROWS, QKVN, D_MODEL);

    rope_split<<<dim3(SEQ / 128, BATCH * NH), 256, 0, stream>>>(qkv, tpos, Qh, Kh, VT);

    flash_attn<<<512, 512, 0, stream>>>(Qh, Kh, VT, AO);

    // out = AO @ w_o^T : M=4096, N=1024, K=1024 (fp32 out)
    gemm_nt<float, 2><<<dim3(32, 16), 256, 0, stream>>>(AO, wob, out, MROWS, D_MODEL, D_MODEL);
}